// Round 1
// baseline (158.622 us; speedup 1.0000x reference)
//
#include <hip/hip_runtime.h>
#include <math.h>

#define SMK    2048
#define TAPS   32
#define OUTLEN (SMK + TAPS - 1)   // 2079
#define PAD    32
#define SLOTS  (PAD + SMK + PAD)  // 2112 float2 slots
#define MDFT   64

// Bijective slot swizzle: spreads 64-lane window reads (64B lane stride)
// across bank pairs. Any bijection works since all LDS reads are single
// 8B slots (ds_read_b64).
__device__ __forceinline__ int swz(int p) { return p ^ ((p >> 4) & 15); }

__global__ __launch_bounds__(256, 4)
void conv_kernel(const float* __restrict__ input,
                 const float* __restrict__ cof,
                 float* __restrict__ out0)
{
    __shared__ float2 s_sig[SLOTS];
    __shared__ float2 s_tap[TAPS];
    const int tid = threadIdx.x;
    const int row = blockIdx.x;

    // ---- stage signal row (2048 complex = 16KB) into swizzled LDS ----
    const float4* gin = (const float4*)(input + (size_t)row * SMK * 2);
    #pragma unroll
    for (int k = 0; k < 4; ++k) {
        float4 v = gin[tid + 256 * k];
        int i0 = PAD + 2 * (tid + 256 * k);
        s_sig[swz(i0)]     = make_float2(v.x, v.y);
        s_sig[swz(i0 + 1)] = make_float2(v.z, v.w);
    }
    // zero pads front [0,32) and back [2080,2112)
    if (tid < PAD) {
        s_sig[swz(tid)] = make_float2(0.f, 0.f);
    } else if (tid < 2 * PAD) {
        s_sig[swz(PAD + SMK + (tid - PAD))] = make_float2(0.f, 0.f);
    }
    if (tid < TAPS) {
        const float2* ct = (const float2*)(cof + (size_t)row * TAPS * 2);
        s_tap[tid] = ct[tid];
    }
    __syncthreads();

    // ---- each thread: 8 consecutive outputs t0..t0+7 ----
    const int t0 = tid * 8;

    // window sig[t0-31 .. t0+7] -> padded slot p = t0+1+m
    float2 win[39];
    #pragma unroll
    for (int m = 0; m < 39; ++m) win[m] = s_sig[swz(t0 + 1 + m)];

    float2 acc[8];
    #pragma unroll
    for (int k = 0; k < 8; ++k) acc[k] = make_float2(0.f, 0.f);

    #pragma unroll
    for (int l = 0; l < TAPS; ++l) {
        float2 h = s_tap[l];   // wave-uniform broadcast read
        #pragma unroll
        for (int k = 0; k < 8; ++k) {
            float2 s = win[k + 31 - l];   // sig[t0+k-l]
            acc[k].x = fmaf(s.x, h.x, fmaf(-s.y, h.y, acc[k].x));
            acc[k].y = fmaf(s.x, h.y, fmaf( s.y, h.x, acc[k].y));
        }
    }

    float2* go = (float2*)(out0 + (size_t)row * OUTLEN * 2);
    #pragma unroll
    for (int k = 0; k < 8; ++k) go[t0 + k] = acc[k];

    // ---- tail outputs t = 2048..2078 (31 of them) ----
    if (tid < OUTLEN - SMK) {
        int t = SMK + tid;
        float2 a = make_float2(0.f, 0.f);
        #pragma unroll
        for (int l = 0; l < TAPS; ++l) {
            float2 h = s_tap[l];
            float2 s = s_sig[swz(t - l + PAD)];  // top pads are zero
            a.x = fmaf(s.x, h.x, fmaf(-s.y, h.y, a.x));
            a.y = fmaf(s.x, h.y, fmaf( s.y, h.x, a.y));
        }
        go[t] = a;
    }
}

// H_t[row][k] = sum_{l<32} h[l] * exp(-2*pi*i*k*l/64), k = 0..63
__global__ __launch_bounds__(256)
void dft_kernel(const float* __restrict__ cof,
                float* __restrict__ out1)
{
    __shared__ float2 tw[MDFT];
    __shared__ float  taps[256];   // 4 rows x 32 complex = 256 floats
    const int tid = threadIdx.x;
    const int r0  = blockIdx.x * 4;

    if (tid < MDFT) {
        float ang = -2.0f * (float)M_PI * (float)tid / (float)MDFT;
        tw[tid] = make_float2(cosf(ang), sinf(ang));
    }
    // 4 consecutive rows of taps: 256 contiguous floats
    taps[tid] = cof[(size_t)r0 * TAPS * 2 + tid];
    __syncthreads();

    const int sub = tid >> 6;          // row within block (wave-uniform)
    const int k   = tid & 63;          // frequency bin = lane
    const float2* h = (const float2*)&taps[sub * TAPS * 2];

    float2 a = make_float2(0.f, 0.f);
    #pragma unroll
    for (int l = 0; l < TAPS; ++l) {
        float2 hv = h[l];              // wave-uniform broadcast
        float2 w  = tw[(k * l) & (MDFT - 1)];
        a.x = fmaf(hv.x, w.x, fmaf(-hv.y, w.y, a.x));
        a.y = fmaf(hv.x, w.y, fmaf( hv.y, w.x, a.y));
    }
    ((float2*)out1)[(size_t)(r0 + sub) * MDFT + k] = a;
}

extern "C" void kernel_launch(void* const* d_in, const int* in_sizes, int n_in,
                              void* d_out, int out_size, void* d_ws, size_t ws_size,
                              hipStream_t stream)
{
    const float* input = (const float*)d_in[0];  // (N,P,2048,2) fp32
    const float* cof   = (const float*)d_in[1];  // (N,P,32,2)   fp32
    // d_in[2] is M (=64), compile-time here.

    const int NP = in_sizes[0] / (SMK * 2);      // 16384

    float* out0 = (float*)d_out;                           // (NP, 2079, 2)
    float* out1 = out0 + (size_t)NP * OUTLEN * 2;          // (NP, 64, 2)

    conv_kernel<<<NP, 256, 0, stream>>>(input, cof, out0);
    dft_kernel<<<NP / 4, 256, 0, stream>>>(cof, out1);
}

// Round 2
// 154.818 us; speedup vs baseline: 1.0246x; 1.0246x over previous
//
#include <hip/hip_runtime.h>
#include <math.h>

#define SMK    2048
#define TAPS   32
#define OUTLEN (SMK + TAPS - 1)   // 2079
#define PAD    32
#define SLOTS  (PAD + SMK + PAD)  // 2112 float2 slots
#define MDFT   64
#define NF4    1040               // ceil(OUTLEN/2) float4 slots for out staging

// Bijective slot swizzle for the signal buffer (8B-slot granularity).
__device__ __forceinline__ int swz(int p) { return p ^ ((p >> 4) & 15); }
// Bijective swizzle at float4-slot granularity for the output staging buffer:
// write side (lane i -> slots 4i+k) and read side (lane i -> slot i+256*it)
// both land at <=2-way bank conflicts.
__device__ __forceinline__ int swz4(int s) { return s ^ ((s >> 3) & 7); }

__device__ __forceinline__ float rfl(float x) {
    return __int_as_float(__builtin_amdgcn_readfirstlane(__float_as_int(x)));
}

__global__ __launch_bounds__(256, 4)
void conv_kernel(const float* __restrict__ input,
                 const float* __restrict__ cof,
                 float* __restrict__ out0,
                 float* __restrict__ out1)
{
    __shared__ float2 s_sig[SLOTS];
    __shared__ float4 s_out[NF4];
    __shared__ float2 s_tap[TAPS];
    __shared__ float2 s_tw[MDFT];

    const int tid = threadIdx.x;
    const int row = blockIdx.x;

    // ---- stage signal row (2048 complex = 16KB) into swizzled LDS ----
    const float4* gin = (const float4*)(input + (size_t)row * SMK * 2);
    #pragma unroll
    for (int k = 0; k < 4; ++k) {
        float4 v = gin[tid + 256 * k];
        int i0 = PAD + 2 * (tid + 256 * k);
        s_sig[swz(i0)]     = make_float2(v.x, v.y);
        s_sig[swz(i0 + 1)] = make_float2(v.z, v.w);
    }
    // zero pads front [0,32) and back [2080,2112)
    if (tid < PAD) {
        s_sig[swz(tid)] = make_float2(0.f, 0.f);
    } else if (tid < 2 * PAD) {
        s_sig[swz(SMK + tid)] = make_float2(0.f, 0.f);   // PAD+SMK+(tid-PAD)
    }
    if (tid < TAPS) {
        const float2* ct = (const float2*)(cof + (size_t)row * TAPS * 2);
        s_tap[tid] = ct[tid];
    }
    // twiddle table for the fused 64-pt DFT: e^{-2*pi*i*j/64}
    if (tid >= 64 && tid < 128) {
        int j = tid - 64;
        float sv, cv;
        __sincosf(-2.0f * (float)M_PI * (float)j / (float)MDFT, &sv, &cv);
        s_tw[j] = make_float2(cv, sv);
    }
    __syncthreads();

    // ---- taps -> SGPRs (block-uniform) ----
    float hre[TAPS], him[TAPS];
    #pragma unroll
    for (int l = 0; l < TAPS; ++l) {
        float2 h = s_tap[l];
        hre[l] = rfl(h.x);
        him[l] = rfl(h.y);
    }

    // ---- each thread: 8 consecutive outputs t0..t0+7, register window ----
    const int t0 = tid * 8;

    float2 win[39];                       // sig[t0-31 .. t0+7]
    #pragma unroll
    for (int m = 0; m < 39; ++m) win[m] = s_sig[swz(t0 + 1 + m)];

    float2 acc[8];
    #pragma unroll
    for (int k = 0; k < 8; ++k) acc[k] = make_float2(0.f, 0.f);

    #pragma unroll
    for (int l = 0; l < TAPS; ++l) {
        const float hr = hre[l];
        const float hi = him[l];
        #pragma unroll
        for (int k = 0; k < 8; ++k) {
            float2 s = win[k + 31 - l];   // sig[t0+k-l]
            acc[k].x = fmaf(s.x, hr, fmaf(-s.y, hi, acc[k].x));
            acc[k].y = fmaf(s.x, hi, fmaf( s.y, hr, acc[k].y));
        }
    }

    // ---- stage results into swizzled s_out (float4 granularity) ----
    #pragma unroll
    for (int k = 0; k < 4; ++k) {
        float4 v = make_float4(acc[2 * k].x, acc[2 * k].y,
                               acc[2 * k + 1].x, acc[2 * k + 1].y);
        s_out[swz4(4 * tid + k)] = v;
    }

    // ---- tail outputs t = 2048..2078 (31 of them) into s_out ----
    if (tid < OUTLEN - SMK) {
        const int t = SMK + tid;
        float2 a = make_float2(0.f, 0.f);
        #pragma unroll
        for (int l = 0; l < TAPS; ++l) {
            float2 s = s_sig[swz(t - l + PAD)];  // top pads are zero
            a.x = fmaf(s.x, hre[l], fmaf(-s.y, him[l], a.x));
            a.y = fmaf(s.x, him[l], fmaf( s.y, hre[l], a.y));
        }
        float2* so2 = (float2*)s_out;
        so2[swz4(t >> 1) * 2 + (t & 1)] = a;
    }

    // ---- fused 64-pt DFT of zero-padded taps (wave 0 only) ----
    if (tid < MDFT) {
        const int k = tid;
        float2 a = make_float2(0.f, 0.f);
        #pragma unroll
        for (int l = 0; l < TAPS; ++l) {
            float2 w = s_tw[(k * l) & (MDFT - 1)];
            a.x = fmaf(w.x, hre[l], fmaf(-w.y, him[l], a.x));
            a.y = fmaf(w.y, hre[l], fmaf( w.x, him[l], a.y));
        }
        ((float2*)out1)[(size_t)row * MDFT + k] = a;
    }

    __syncthreads();

    // ---- coalesced float2 stores: lanes contiguous per instruction ----
    const float2* so2 = (const float2*)s_out;
    float2* go2 = (float2*)(out0 + (size_t)row * OUTLEN * 2);
    #pragma unroll
    for (int it = 0; it < 8; ++it) {
        int s2 = tid + 256 * it;          // 0..2047
        go2[s2] = so2[swz4(s2 >> 1) * 2 + (s2 & 1)];
    }
    {
        int s2 = tid + 2048;              // tail 2048..2078
        if (s2 < OUTLEN)
            go2[s2] = so2[swz4(s2 >> 1) * 2 + (s2 & 1)];
    }
}

extern "C" void kernel_launch(void* const* d_in, const int* in_sizes, int n_in,
                              void* d_out, int out_size, void* d_ws, size_t ws_size,
                              hipStream_t stream)
{
    const float* input = (const float*)d_in[0];  // (N,P,2048,2) fp32
    const float* cof   = (const float*)d_in[1];  // (N,P,32,2)   fp32
    // d_in[2] is M (=64), compile-time here.

    const int NP = in_sizes[0] / (SMK * 2);      // 16384

    float* out0 = (float*)d_out;                           // (NP, 2079, 2)
    float* out1 = out0 + (size_t)NP * OUTLEN * 2;          // (NP, 64, 2)

    conv_kernel<<<NP, 256, 0, stream>>>(input, cof, out0, out1);
}